// Round 12
// baseline (663.267 us; speedup 1.0000x reference)
//
#include <hip/hip_runtime.h>
#include <hip/hip_bf16.h>

#define N_NODES 50000
#define N_EDGES 800000
#define N_GRAPHS 64
#define IN_DIM 384
#define HID 128
#define MLP_HID 64

#define NB 16                 // src buckets
#define BSH 12                // bucket = src >> 12  (4096 nodes = 2 MiB window)
#define NTOT (N_NODES * NB)   // 800000 segment counters
#define BS2_BLOCKS ((NTOT + 1023) / 1024)   // 782
#define GEMM_BLOCKS ((N_NODES + 127) / 128) // 391
#define GATH_BLOCKS ((N_NODES + 31) / 32)   // 1563 (4 waves x 8 dst rows)

typedef __attribute__((ext_vector_type(8))) short short8;
typedef __attribute__((ext_vector_type(4))) float f32x4;
typedef unsigned int u32;

// ---------------------------------------------------------------- count per (dst, src-bucket)
__global__ __launch_bounds__(256) void count2_kernel(const int* __restrict__ ei,
                                                     int* __restrict__ seg, int E) {
    int t = blockIdx.x * 256 + threadIdx.x;
    if (t < E) {
        const int s = ei[t];
        const int d = ei[E + t];
        atomicAdd(&seg[d * NB + (s >> BSH)], 1);
    }
}

// ---------------------------------------------------------------- scan pass 1: block sums (1024 elems/block)
__global__ __launch_bounds__(256) void bsum2_kernel(const int* __restrict__ seg,
                                                    int* __restrict__ bsum) {
    __shared__ int sh[256];
    const int t = threadIdx.x;
    const int i0 = blockIdx.x * 1024 + t * 4;
    int s = 0;
#pragma unroll
    for (int k = 0; k < 4; ++k) {
        const int i = i0 + k;
        if (i < NTOT) s += seg[i];
    }
    sh[t] = s;
    __syncthreads();
#pragma unroll
    for (int off = 128; off > 0; off >>= 1) {
        if (t < off) sh[t] += sh[t + off];
        __syncthreads();
    }
    if (t == 0) bsum[blockIdx.x] = sh[0];
}

// ---------------------------------------------------------------- scan pass 2: scan 782 block sums
__global__ __launch_bounds__(256) void bscan2_kernel(const int* __restrict__ bsum,
                                                     int* __restrict__ boff) {
    __shared__ int sh[256];
    const int t = threadIdx.x;
    int v[4];
    int s = 0;
#pragma unroll
    for (int k = 0; k < 4; ++k) {
        const int i = t * 4 + k;
        v[k] = (i < BS2_BLOCKS) ? bsum[i] : 0;
        s += v[k];
    }
    sh[t] = s;
    __syncthreads();
    for (int off = 1; off < 256; off <<= 1) {
        int u = 0;
        if (t >= off) u = sh[t - off];
        __syncthreads();
        if (t >= off) sh[t] += u;
        __syncthreads();
    }
    int base = sh[t] - s;   // exclusive prefix of this thread's chunk
#pragma unroll
    for (int k = 0; k < 4; ++k) {
        const int i = t * 4 + k;
        if (i < BS2_BLOCKS) boff[i] = base;
        base += v[k];
    }
}

// ---------------------------------------------------------------- scan pass 3: counts -> starts (in place)
__global__ __launch_bounds__(256) void final2_kernel(int* __restrict__ seg,
                                                     const int* __restrict__ boff) {
    __shared__ int sh[256];
    const int t = threadIdx.x;
    const int i0 = blockIdx.x * 1024 + t * 4;
    int c[4];
    int s = 0;
#pragma unroll
    for (int k = 0; k < 4; ++k) {
        const int i = i0 + k;
        c[k] = (i < NTOT) ? seg[i] : 0;
        s += c[k];
    }
    sh[t] = s;
    __syncthreads();
    for (int off = 1; off < 256; off <<= 1) {
        int u = 0;
        if (t >= off) u = sh[t - off];
        __syncthreads();
        if (t >= off) sh[t] += u;
        __syncthreads();
    }
    int run = boff[blockIdx.x] + sh[t] - s;
#pragma unroll
    for (int k = 0; k < 4; ++k) {
        const int i = i0 + k;
        if (i < NTOT) seg[i] = run;
        run += c[k];
    }
}

// ---------------------------------------------------------------- dis from segment starts
__global__ __launch_bounds__(256) void dis2_kernel(const int* __restrict__ seg,
                                                   float* __restrict__ dis) {
    const int d = blockIdx.x * 256 + threadIdx.x;
    if (d < N_NODES) {
        const int start = seg[d * NB];
        const int next = (d == N_NODES - 1) ? N_EDGES : seg[(d + 1) * NB];
        dis[d] = rsqrtf((float)(next - start) + 1.0f);
    }
}

// ---------------------------------------------------------------- CSR fill (starts -> ends in place)
__global__ __launch_bounds__(256) void fill2_kernel(const int* __restrict__ ei,
                                                    int* __restrict__ seg,
                                                    int* __restrict__ csr, int E) {
    int e = blockIdx.x * 256 + threadIdx.x;
    if (e >= E) return;
    const int s = ei[e];
    const int d = ei[E + e];
    const int pos = atomicAdd(&seg[d * NB + (s >> BSH)], 1);
    csr[pos] = s;
}

// ---------------------------------------------------------------- W split (all 3 weights, one dispatch)
__device__ __forceinline__ void wsplit_one(const float* W, ushort* hi, ushort* lo,
                                           int K, int t) {
    const int k = t >> 7;
    const int c = t & 127;
    const float f = W[t];
    const u32 u = __float_as_uint(f);
    const u32 h = u & 0xFFFF0000u;
    const float lf = f - __uint_as_float(h);
    hi[c * K + k] = (ushort)(u >> 16);
    lo[c * K + k] = (ushort)(__float_as_uint(lf) >> 16);
}

__global__ __launch_bounds__(256) void wsplit_kernel(const float* __restrict__ W1,
                                                     const float* __restrict__ W2,
                                                     const float* __restrict__ W3,
                                                     ushort* __restrict__ w1hi, ushort* __restrict__ w1lo,
                                                     ushort* __restrict__ w2hi, ushort* __restrict__ w2lo,
                                                     ushort* __restrict__ w3hi, ushort* __restrict__ w3lo) {
    int t = blockIdx.x * 256 + threadIdx.x;
    if (t < IN_DIM * HID) wsplit_one(W1, w1hi, w1lo, IN_DIM, t);
    if (t < HID * HID) {
        wsplit_one(W2, w2hi, w2lo, HID, t);
        wsplit_one(W3, w3hi, w3lo, HID, t);
    }
}

// ---------------------------------------------------------------- MFMA split-bf16 GEMM
// Hs[M,128] = ((relu?)X[M,K] @ W[K,128]) * dis[row]
template <int K, bool RELU_IN>
__global__ __launch_bounds__(256) void gemm_mfma_kernel(const float* __restrict__ X,
                                                        const ushort* __restrict__ Wthi,
                                                        const ushort* __restrict__ Wtlo,
                                                        const float* __restrict__ dis,
                                                        float* __restrict__ Hs, int M) {
    __shared__ ushort Ahi[128][40];
    __shared__ ushort Alo[128][40];
    __shared__ ushort Bhi[128][40];
    __shared__ ushort Blo[128][40];

    const int tid = threadIdx.x;
    const int row0 = blockIdx.x * 128;

    const int srow = tid >> 1;
    const int skq  = (tid & 1) << 4;

    const int lane = tid & 63;
    const int wave = tid >> 6;
    const int wr = (wave >> 1) * 64;
    const int wc = (wave & 1) * 64;
    const int li = lane & 15;
    const int kb = (lane >> 4) << 3;

    f32x4 acc[4][4];
#pragma unroll
    for (int m = 0; m < 4; ++m)
#pragma unroll
        for (int n = 0; n < 4; ++n) acc[m][n] = (f32x4){0.f, 0.f, 0.f, 0.f};

    for (int k0 = 0; k0 < K; k0 += 32) {
        {
            const int gr = row0 + srow;
            const float* src = &X[(size_t)(gr < M ? gr : (M - 1)) * K + k0 + skq];
            float f[16];
            *reinterpret_cast<float4*>(f)      = *reinterpret_cast<const float4*>(src);
            *reinterpret_cast<float4*>(f + 4)  = *reinterpret_cast<const float4*>(src + 4);
            *reinterpret_cast<float4*>(f + 8)  = *reinterpret_cast<const float4*>(src + 8);
            *reinterpret_cast<float4*>(f + 12) = *reinterpret_cast<const float4*>(src + 12);
            u32 hp[8], lp[8];
#pragma unroll
            for (int i = 0; i < 8; ++i) {
                float f0 = f[2 * i], f1 = f[2 * i + 1];
                if (RELU_IN) { f0 = fmaxf(f0, 0.f); f1 = fmaxf(f1, 0.f); }
                const u32 u0 = __float_as_uint(f0), u1 = __float_as_uint(f1);
                const u32 h0 = u0 & 0xFFFF0000u, h1 = u1 & 0xFFFF0000u;
                const float l0 = f0 - __uint_as_float(h0);
                const float l1 = f1 - __uint_as_float(h1);
                hp[i] = (h0 >> 16) | h1;
                lp[i] = (__float_as_uint(l0) >> 16) | (__float_as_uint(l1) & 0xFFFF0000u);
            }
            u32* dh = (u32*)&Ahi[srow][skq];
            u32* dl = (u32*)&Alo[srow][skq];
            *reinterpret_cast<uint4*>(dh)     = make_uint4(hp[0], hp[1], hp[2], hp[3]);
            *reinterpret_cast<uint4*>(dh + 4) = make_uint4(hp[4], hp[5], hp[6], hp[7]);
            *reinterpret_cast<uint4*>(dl)     = make_uint4(lp[0], lp[1], lp[2], lp[3]);
            *reinterpret_cast<uint4*>(dl + 4) = make_uint4(lp[4], lp[5], lp[6], lp[7]);
        }
        {
            const ushort* sh = &Wthi[srow * K + k0 + skq];
            const ushort* sl = &Wtlo[srow * K + k0 + skq];
            *reinterpret_cast<uint4*>(&Bhi[srow][skq])     = *reinterpret_cast<const uint4*>(sh);
            *reinterpret_cast<uint4*>(&Bhi[srow][skq + 8]) = *reinterpret_cast<const uint4*>(sh + 8);
            *reinterpret_cast<uint4*>(&Blo[srow][skq])     = *reinterpret_cast<const uint4*>(sl);
            *reinterpret_cast<uint4*>(&Blo[srow][skq + 8]) = *reinterpret_cast<const uint4*>(sl + 8);
        }
        __syncthreads();
        short8 ah[4], al[4];
#pragma unroll
        for (int m = 0; m < 4; ++m) {
            ah[m] = *reinterpret_cast<const short8*>(&Ahi[wr + m * 16 + li][kb]);
            al[m] = *reinterpret_cast<const short8*>(&Alo[wr + m * 16 + li][kb]);
        }
#pragma unroll
        for (int n = 0; n < 4; ++n) {
            const short8 bh = *reinterpret_cast<const short8*>(&Bhi[wc + n * 16 + li][kb]);
            const short8 bl = *reinterpret_cast<const short8*>(&Blo[wc + n * 16 + li][kb]);
#pragma unroll
            for (int m = 0; m < 4; ++m) {
                acc[m][n] = __builtin_amdgcn_mfma_f32_16x16x32_bf16(ah[m], bh, acc[m][n], 0, 0, 0);
                acc[m][n] = __builtin_amdgcn_mfma_f32_16x16x32_bf16(ah[m], bl, acc[m][n], 0, 0, 0);
                acc[m][n] = __builtin_amdgcn_mfma_f32_16x16x32_bf16(al[m], bh, acc[m][n], 0, 0, 0);
            }
        }
        __syncthreads();
    }
    const int rbase = (lane >> 4) << 2;
#pragma unroll
    for (int m = 0; m < 4; ++m) {
        const int gr0 = row0 + wr + m * 16 + rbase;
#pragma unroll
        for (int r = 0; r < 4; ++r) {
            const int grow = gr0 + r;
            if (grow < M) {
                const float dv = dis[grow];
#pragma unroll
                for (int n = 0; n < 4; ++n) {
                    Hs[(size_t)grow * 128 + wc + n * 16 + li] = acc[m][n][r] * dv;
                }
            }
        }
    }
}

// ---------------------------------------------------------------- bucketed gather
// Wave owns 8 dst rows, register accumulators (float2/lane). Bucket-outer loop:
// all resident waves sweep the same 2 MiB src window -> L2-resident gathers.
// Carried cursor pc[r]: one seg[] load per (row,bucket). All bounds wave-uniform.
// seg[] holds segment ENDS (post-fill); start of (d,0) = end of (d-1,NB-1).
template <bool POOL>
__global__ __launch_bounds__(256) void gather2_kernel(const int* __restrict__ seg,
                                                      const int* __restrict__ csr,
                                                      const float* __restrict__ Hs,
                                                      const float* __restrict__ dis,
                                                      const float* __restrict__ bias,
                                                      float* __restrict__ AGG,
                                                      const int* __restrict__ batch,
                                                      float* __restrict__ pooled) {
    const int wave = threadIdx.x >> 6;
    const int lane = threadIdx.x & 63;
    const int dBlk = blockIdx.x * 32;
    const int d0 = dBlk + wave * 8;
    const int f = lane * 2;
    int nrows = N_NODES - d0;
    nrows = nrows < 0 ? 0 : (nrows > 8 ? 8 : nrows);

    float2 acc[8];
    int pc[8];
#pragma unroll
    for (int r = 0; r < 8; ++r) {
        if (r < nrows) {
            const int d = d0 + r;
            acc[r] = *reinterpret_cast<const float2*>(&Hs[(size_t)d * 128 + f]);  // self
            pc[r] = (d == 0) ? 0 : seg[d * NB - 1];
        } else {
            acc[r] = make_float2(0.f, 0.f);
            pc[r] = 0;
        }
    }

    for (int b = 0; b < NB; ++b) {
#pragma unroll
        for (int r = 0; r < 8; ++r) {
            if (r >= nrows) break;                       // wave-uniform
            const int p1 = seg[(d0 + r) * NB + b];
            for (int e = pc[r]; e < p1; ++e) {
                const int s = csr[e];
                const float2 v = *reinterpret_cast<const float2*>(&Hs[(size_t)s * 128 + f]);
                acc[r].x += v.x;
                acc[r].y += v.y;
            }
            pc[r] = p1;
        }
    }

    if (!POOL) {
#pragma unroll
        for (int r = 0; r < 8; ++r) {
            if (r >= nrows) break;
            const int d = d0 + r;
            const float dv = dis[d];
            float2 o;
            o.x = fmaf(acc[r].x, dv, bias[f]);
            o.y = fmaf(acc[r].y, dv, bias[f + 1]);
            *reinterpret_cast<float2*>(&AGG[(size_t)d * 128 + f]) = o;
        }
    } else {
        __shared__ float part[32][128];
#pragma unroll
        for (int r = 0; r < 8; ++r) {
            float2 o = make_float2(0.f, 0.f);
            if (r < nrows) {
                const float dv = dis[d0 + r];
                o.x = fmaxf(fmaf(acc[r].x, dv, bias[f]), 0.f);
                o.y = fmaxf(fmaf(acc[r].y, dv, bias[f + 1]), 0.f);
            }
            part[wave * 8 + r][f] = o.x;
            part[wave * 8 + r][f + 1] = o.y;
        }
        __syncthreads();
        if (threadIdx.x < 128) {
            const int fq = threadIdx.x;
            float s = 0.f;
            int gcur = -1;
            for (int r = 0; r < 32; ++r) {
                const int d = dBlk + r;
                if (d >= N_NODES) break;
                const int g = batch[d];
                if (g != gcur) {
                    if (gcur >= 0) atomicAdd(&pooled[gcur * HID + fq], s);
                    gcur = g;
                    s = 0.f;
                }
                s += part[r][fq];
            }
            if (gcur >= 0) atomicAdd(&pooled[gcur * HID + fq], s);
        }
    }
}

// ---------------------------------------------------------------- pool stage 2: divide by counts
__global__ __launch_bounds__(128) void pooldiv_kernel(const int* __restrict__ batch,
                                                      float* __restrict__ pooled, int n) {
    const int g = blockIdx.x;
    int lo = 0, hi = n;
    while (lo < hi) { int mid = (lo + hi) >> 1; if (batch[mid] < g) lo = mid + 1; else hi = mid; }
    const int start = lo;
    hi = n;
    while (lo < hi) { int mid = (lo + hi) >> 1; if (batch[mid] < g + 1) lo = mid + 1; else hi = mid; }
    const float cnt = (float)(lo - start);
    pooled[g * HID + threadIdx.x] /= fmaxf(cnt, 1.f);
}

// ---------------------------------------------------------------- MLP head
__global__ __launch_bounds__(256) void mlp_kernel(const float* __restrict__ pooled,
                                                  const float* __restrict__ Wm1,
                                                  const float* __restrict__ bm1,
                                                  const float* __restrict__ Wm2,
                                                  const float* __restrict__ bm2,
                                                  float* __restrict__ out) {
    __shared__ float P[N_GRAPHS][HID];
    __shared__ float Wl[HID][MLP_HID];
    const int tid = threadIdx.x;
    for (int i = tid; i < N_GRAPHS * HID; i += 256) P[i >> 7][i & 127] = pooled[i];
    for (int i = tid; i < HID * MLP_HID; i += 256) Wl[i >> 6][i & 63] = Wm1[i];
    __syncthreads();
    const int g = tid >> 2;
    const int jb = tid & 3;
    float part = 0.f;
#pragma unroll
    for (int jj = 0; jj < 16; ++jj) {
        const int j = jb * 16 + jj;
        float z = bm1[j];
        for (int k = 0; k < HID; ++k) z = fmaf(P[g][k], Wl[k][j], z);
        z = fmaxf(z, 0.f);
        part = fmaf(z, Wm2[j], part);
    }
    part += __shfl_xor(part, 1);
    part += __shfl_xor(part, 2);
    if (jb == 0) out[g] = part + bm2[0];
}

extern "C" void kernel_launch(void* const* d_in, const int* in_sizes, int n_in,
                              void* d_out, int out_size, void* d_ws, size_t ws_size,
                              hipStream_t stream) {
    const float* x   = (const float*)d_in[0];
    const int*   ei  = (const int*)d_in[1];
    const int*   bat = (const int*)d_in[2];
    const float* W1  = (const float*)d_in[3];
    const float* b1  = (const float*)d_in[4];
    const float* W2  = (const float*)d_in[5];
    const float* b2  = (const float*)d_in[6];
    const float* W3  = (const float*)d_in[7];
    const float* b3  = (const float*)d_in[8];
    const float* Wm1 = (const float*)d_in[9];
    const float* bm1 = (const float*)d_in[10];
    const float* Wm2 = (const float*)d_in[11];
    const float* bm2 = (const float*)d_in[12];
    float* out = (float*)d_out;

    int*   seg    = (int*)d_ws;                 // 800000 (counts -> starts -> ends)
    int*   csr    = seg + NTOT;                 // 800000
    int*   bsum2  = csr + 800000;               // 1024
    int*   boff2  = bsum2 + 1024;               // 1024
    float* dis    = (float*)(boff2 + 1024);     // 50048
    float* Hs     = dis + 50048;                // 6.4M (dis-prescaled H)
    float* AGG    = Hs + N_NODES * HID;         // 6.4M
    float* pooled = AGG + N_NODES * HID;        // 8192
    ushort* wt1hi = (ushort*)(pooled + 8192);
    ushort* wt1lo = wt1hi + IN_DIM * HID;
    ushort* wt2hi = wt1lo + IN_DIM * HID;
    ushort* wt2lo = wt2hi + HID * HID;
    ushort* wt3hi = wt2lo + HID * HID;
    ushort* wt3lo = wt3hi + HID * HID;

    hipMemsetAsync(seg, 0, NTOT * sizeof(int), stream);
    hipMemsetAsync(pooled, 0, N_GRAPHS * HID * sizeof(float), stream);

    count2_kernel<<<(N_EDGES + 255) / 256, 256, 0, stream>>>(ei, seg, N_EDGES);
    bsum2_kernel<<<BS2_BLOCKS, 256, 0, stream>>>(seg, bsum2);
    bscan2_kernel<<<1, 256, 0, stream>>>(bsum2, boff2);
    final2_kernel<<<BS2_BLOCKS, 256, 0, stream>>>(seg, boff2);
    dis2_kernel<<<(N_NODES + 255) / 256, 256, 0, stream>>>(seg, dis);
    fill2_kernel<<<(N_EDGES + 255) / 256, 256, 0, stream>>>(ei, seg, csr, N_EDGES);

    wsplit_kernel<<<(IN_DIM * HID + 255) / 256, 256, 0, stream>>>(
        W1, W2, W3, wt1hi, wt1lo, wt2hi, wt2lo, wt3hi, wt3lo);

    // layer 1
    gemm_mfma_kernel<IN_DIM, false><<<GEMM_BLOCKS, 256, 0, stream>>>(x, wt1hi, wt1lo, dis, Hs, N_NODES);
    gather2_kernel<false><<<GATH_BLOCKS, 256, 0, stream>>>(seg, csr, Hs, dis, b1, AGG, bat, pooled);
    // layer 2
    gemm_mfma_kernel<HID, true><<<GEMM_BLOCKS, 256, 0, stream>>>(AGG, wt2hi, wt2lo, dis, Hs, N_NODES);
    gather2_kernel<false><<<GATH_BLOCKS, 256, 0, stream>>>(seg, csr, Hs, dis, b2, AGG, bat, pooled);
    // layer 3
    gemm_mfma_kernel<HID, true><<<GEMM_BLOCKS, 256, 0, stream>>>(AGG, wt3hi, wt3lo, dis, Hs, N_NODES);
    gather2_kernel<true><<<GATH_BLOCKS, 256, 0, stream>>>(seg, csr, Hs, dis, b3, AGG, bat, pooled);

    pooldiv_kernel<<<N_GRAPHS, 128, 0, stream>>>(bat, pooled, N_NODES);
    mlp_kernel<<<1, 256, 0, stream>>>(pooled, Wm1, bm1, Wm2, bm2, out);
}